// Round 11
// baseline (80.111 us; speedup 1.0000x reference)
//
#include <hip/hip_runtime.h>

// Problem constants
#define BB 8
#define FF 256
#define TT 1024
#define CC 64
constexpr float EPS = 1e-9f;

// pass B tiling (round-3 verbatim)
#define BT 64               // t-chunk
#define NTQ 16              // TT / BT
#define NTILE 64            // phase-1 tiles per b
#define BCF (BB * CC * FF)  // 131072

// ws layout (float offsets) — round-3 verbatim
#define WS_R   0            // r[B][C][T]        524288
#define WS_NP  524288       // Npart[512][64]     32768
#define WS_FP  557056       // Fpart[16][B][C][F] 2097152

// ---------------------------------------------------------------------------
// phase 1 (simplified): per (b, 16-t tile): mu2/p2 inline, stage x^T, then
// per-thread full-K GEMM (t, 4 c's) with x2 folded in, softmax over c via
// 16-lane shuffles, write r[b][c][t] + N partial. 2 barriers, no Sred.
// grid = 512 (b(8) x tile(64)).
// ---------------------------------------------------------------------------
__global__ __launch_bounds__(256, 4) void k_phase1(
        const float* __restrict__ x, const float* __restrict__ mu,
        const float* __restrict__ prec, float* __restrict__ ws) {
    __shared__ __align__(16) float xt[16][260];   // [t][f]
    __shared__ __align__(16) float rl[16][68];    // r[t][c]
    __shared__ float mu2s[CC], p2s[CC];

    const int tid = threadIdx.x;
    const int b    = blockIdx.x >> 6;
    const int tile = blockIdx.x & 63;
    const int t0   = tile * 16;
    const float* xb = x + (size_t)b * FF * TT;

    // mu2[c], p2[c] inline (pre-barrier; independent of x staging)
    {
        const int c = tid >> 2, q = tid & 3;
        const float* mp = mu + c * FF + q * 64;
        float s = 0.f;
        #pragma unroll
        for (int i = 0; i < 16; ++i) {
            float4 v = *(const float4*)(mp + i * 4);
            s += v.x * v.x + v.y * v.y + v.z * v.z + v.w * v.w;
        }
        s += __shfl_xor(s, 1);
        s += __shfl_xor(s, 2);
        if (q == 0) mu2s[c] = s;
        if (tid < CC) { float p = prec[tid]; p2s[tid] = p * p; }
    }

    // stage x[b][:, t0..t0+16) transposed -> xt[t][f]
    #pragma unroll
    for (int it = 0; it < 4; ++it) {
        const int id = it * 256 + tid;
        const int f = id >> 2, seg = id & 3;
        float4 v = *(const float4*)(xb + f * TT + t0 + seg * 4);
        xt[seg * 4 + 0][f] = v.x;
        xt[seg * 4 + 1][f] = v.y;
        xt[seg * 4 + 2][f] = v.z;
        xt[seg * 4 + 3][f] = v.w;
    }
    __syncthreads();

    // per-thread GEMM1 over full K=256: thread (tc=c-group, tg=t) ; x2 inline
    {
        const int tc = tid & 15, tg = tid >> 4;
        const int c4 = tc * 4;
        float acc0 = 0.f, acc1 = 0.f, acc2 = 0.f, acc3 = 0.f, x2v = 0.f;
        const float* mup = mu + (size_t)c4 * FF;
        #pragma unroll 4
        for (int kk = 0; kk < 64; ++kk) {
            float4 xv = *(const float4*)&xt[tg][kk * 4];
            x2v += xv.x * xv.x + xv.y * xv.y + xv.z * xv.z + xv.w * xv.w;
            float4 m0 = *(const float4*)(mup + 0 * FF + kk * 4);
            float4 m1 = *(const float4*)(mup + 1 * FF + kk * 4);
            float4 m2 = *(const float4*)(mup + 2 * FF + kk * 4);
            float4 m3 = *(const float4*)(mup + 3 * FF + kk * 4);
            acc0 += xv.x * m0.x + xv.y * m0.y + xv.z * m0.z + xv.w * m0.w;
            acc1 += xv.x * m1.x + xv.y * m1.y + xv.z * m1.z + xv.w * m1.w;
            acc2 += xv.x * m2.x + xv.y * m2.y + xv.z * m2.z + xv.w * m2.w;
            acc3 += xv.x * m3.x + xv.y * m3.y + xv.z * m3.z + xv.w * m3.w;
        }

        // llk + softmax over 64 c (16-lane group shuffles; lanes share tg)
        float l0 = -p2s[c4 + 0] * (x2v - 2.f * acc0 + mu2s[c4 + 0]);
        float l1 = -p2s[c4 + 1] * (x2v - 2.f * acc1 + mu2s[c4 + 1]);
        float l2 = -p2s[c4 + 2] * (x2v - 2.f * acc2 + mu2s[c4 + 2]);
        float l3 = -p2s[c4 + 3] * (x2v - 2.f * acc3 + mu2s[c4 + 3]);
        float m = fmaxf(fmaxf(l0, l1), fmaxf(l2, l3));
        m = fmaxf(m, __shfl_xor(m, 1));
        m = fmaxf(m, __shfl_xor(m, 2));
        m = fmaxf(m, __shfl_xor(m, 4));
        m = fmaxf(m, __shfl_xor(m, 8));
        float e0 = __expf(l0 - m), e1 = __expf(l1 - m);
        float e2 = __expf(l2 - m), e3 = __expf(l3 - m);
        float sum = e0 + e1 + e2 + e3;
        sum += __shfl_xor(sum, 1);
        sum += __shfl_xor(sum, 2);
        sum += __shfl_xor(sum, 4);
        sum += __shfl_xor(sum, 8);
        const float inv = 1.f / sum;
        *(float4*)&rl[tg][c4] = make_float4(e0 * inv, e1 * inv, e2 * inv, e3 * inv);
    }
    __syncthreads();

    // N partial
    if (tid < CC) {
        float ns = 0.f;
        #pragma unroll
        for (int t = 0; t < 16; ++t) ns += rl[t][tid];
        ws[WS_NP + (size_t)blockIdx.x * CC + tid] = ns;
    }

    // r writeout [b][c][t] (round-3 pattern)
    {
        const int c = tid >> 2, seg = tid & 3;
        float4 v;
        v.x = rl[seg * 4 + 0][c];
        v.y = rl[seg * 4 + 1][c];
        v.z = rl[seg * 4 + 2][c];
        v.w = rl[seg * 4 + 3][c];
        *(float4*)(ws + WS_R + ((size_t)b * CC + c) * TT + t0 + seg * 4) = v;
    }
}

// ---------------------------------------------------------------------------
// phase 2 (round-3 verbatim): Fpart[tq][b][c][f0..f0+64) over a 64-t chunk.
// grid = 512: b(8) x fsl(4) x tq(16). 4c x 4f per thread.
// ---------------------------------------------------------------------------
__global__ __launch_bounds__(256) void k_phase2(const float* __restrict__ x,
                                                float* __restrict__ ws) {
    __shared__ float xs[BT][68];   // [t][f'] (+pad)
    __shared__ float rs[CC][68];   // [t][c]  (+pad)
    const int tid = threadIdx.x;
    const int bid = blockIdx.x;
    const int b   = bid >> 6;
    const int fsl = (bid >> 4) & 3;
    const int tq  = bid & 15;
    const int f0  = fsl * 64;
    const int t0  = tq * BT;
    const float* xb = x + (size_t)b * FF * TT;
    const float* rb = ws + WS_R + (size_t)b * CC * TT;

    #pragma unroll
    for (int it = 0; it < 4; ++it) {
        const int id = it * 256 + tid;
        {   // x tile: transpose into xs[t][f']
            const int ff = id >> 4, seg = id & 15;
            float4 v = *(const float4*)(xb + (f0 + ff) * TT + t0 + seg * 4);
            xs[seg * 4 + 0][ff] = v.x;
            xs[seg * 4 + 1][ff] = v.y;
            xs[seg * 4 + 2][ff] = v.z;
            xs[seg * 4 + 3][ff] = v.w;
        }
        {   // r tile: transpose into rs[t][c]
            const int c = id >> 4, cs = id & 15;
            float4 v = *(const float4*)(rb + (size_t)c * TT + t0 + cs * 4);
            rs[cs * 4 + 0][c] = v.x;
            rs[cs * 4 + 1][c] = v.y;
            rs[cs * 4 + 2][c] = v.z;
            rs[cs * 4 + 3][c] = v.w;
        }
    }
    __syncthreads();

    const int fi = tid & 15, cg = tid >> 4;
    float acc[4][4];
    #pragma unroll
    for (int j = 0; j < 4; ++j)
        #pragma unroll
        for (int e = 0; e < 4; ++e) acc[j][e] = 0.f;

    #pragma unroll 8
    for (int t = 0; t < BT; ++t) {
        float4 xv = *(const float4*)&xs[t][fi * 4];
        float4 rv = *(const float4*)&rs[t][cg * 4];
        acc[0][0] += rv.x * xv.x; acc[0][1] += rv.x * xv.y;
        acc[0][2] += rv.x * xv.z; acc[0][3] += rv.x * xv.w;
        acc[1][0] += rv.y * xv.x; acc[1][1] += rv.y * xv.y;
        acc[1][2] += rv.y * xv.z; acc[1][3] += rv.y * xv.w;
        acc[2][0] += rv.z * xv.x; acc[2][1] += rv.z * xv.y;
        acc[2][2] += rv.z * xv.z; acc[2][3] += rv.z * xv.w;
        acc[3][0] += rv.w * xv.x; acc[3][1] += rv.w * xv.y;
        acc[3][2] += rv.w * xv.z; acc[3][3] += rv.w * xv.w;
    }

    float* fp = ws + WS_FP + (size_t)tq * BCF + (size_t)b * CC * FF;
    #pragma unroll
    for (int j = 0; j < 4; ++j)
        *(float4*)(fp + (size_t)(cg * 4 + j) * FF + f0 + fi * 4) =
            make_float4(acc[j][0], acc[j][1], acc[j][2], acc[j][3]);
}

// ---------------------------------------------------------------------------
// phase 3 (round-3 verbatim): out = (sum_p Fp - N*mu) / (N + eps). grid 512.
// ---------------------------------------------------------------------------
__global__ __launch_bounds__(256) void k_phase3(const float* __restrict__ mu,
                                                const float* __restrict__ ws,
                                                float* __restrict__ out) {
    const int b = blockIdx.x >> 6, c = blockIdx.x & 63;
    const int f = threadIdx.x;
    float nr = 0.f;
    const float* np = ws + WS_NP + (size_t)b * NTILE * CC + c;
    #pragma unroll
    for (int tile = 0; tile < NTILE; ++tile) nr += np[tile * CC];
    const float* fp = ws + WS_FP + (size_t)b * CC * FF + c * FF + f;
    float s = 0.f;
    #pragma unroll
    for (int p = 0; p < NTQ; ++p) s += fp[(size_t)p * BCF];
    out[((size_t)b * CC + c) * FF + f] = (s - nr * mu[c * FF + f]) / (nr + EPS);
}

extern "C" void kernel_launch(void* const* d_in, const int* in_sizes, int n_in,
                              void* d_out, int out_size, void* d_ws, size_t ws_size,
                              hipStream_t stream) {
    const float* x    = (const float*)d_in[0];
    const float* mu   = (const float*)d_in[1];
    const float* prec = (const float*)d_in[2];
    float* out = (float*)d_out;
    float* ws  = (float*)d_ws;

    k_phase1<<<512, 256, 0, stream>>>(x, mu, prec, ws);
    k_phase2<<<512, 256, 0, stream>>>(x, ws);
    k_phase3<<<512, 256, 0, stream>>>(mu, ws, out);
}